// Round 6
// baseline (1389.544 us; speedup 1.0000x reference)
//
#include <hip/hip_runtime.h>
#include <hip/hip_bf16.h>
#include <math.h>

#define B_  512
#define DM  1024
#define DI  2048
#define DS  64
#define DTR 64
#define DT  64
#define G_  8
#define E_  4
#define DC  4
#define GRID 768

typedef __bf16 bf16x8 __attribute__((ext_vector_type(8)));
typedef float  f32x4  __attribute__((ext_vector_type(4)));
typedef unsigned short ushort_t;

__device__ __forceinline__ float bf2f(__hip_bfloat16 h) { return __bfloat162float(h); }
__device__ __forceinline__ __hip_bfloat16 f2bf(float f) { return __float2bfloat16(f); }
__device__ __forceinline__ float sigmoidf_(float x){ return 1.f/(1.f+expf(-x)); }
__device__ __forceinline__ float siluf_(float x){ return x*sigmoidf_(x); }
__device__ __forceinline__ float softplusf_(float x){ return (x>20.f)? x : log1pf(expf(x)); }

__device__ __forceinline__ unsigned int pack2(float a, float b) {
  unsigned short ua = __builtin_bit_cast(unsigned short, (__bf16)a);
  unsigned short ub = __builtin_bit_cast(unsigned short, (__bf16)b);
  return (unsigned int)ua | ((unsigned int)ub << 16);
}
__device__ __forceinline__ uint2 pack4(float4 v) {
  uint2 o; o.x = pack2(v.x, v.y); o.y = pack2(v.z, v.w); return o;
}

struct P {
  const float *uk, *W_in, *b_in, *tk_c, *tk_p, *rW, *rb, *freq, *phase, *kanW;
  const float *W_inproj, *conv_w, *conv_b, *W_x, *W_dt, *dt_bias, *W_delta, *D_skip, *W_out;
  __hip_bfloat16 *ukb, *Winb, *Wipb, *Wxb, *Woutb, *Wcat;   // stage-0 bf16 copies
  __hip_bfloat16 *Pu, *Xs, *Sz, *Yb, *Acat;
  float *Xdbl, *bc;
  int *bar;
  float *out_hk, *out_w, *out_mask;
};

// Software grid barrier (validated round 5). Safe: LDS 38.9KB -> 4 blk/CU,
// launch_bounds(256,4) -> VGPR<=128 -> 4 blk/CU; capacity 1024 >= grid 768.
__device__ __forceinline__ void gsync(int* cnt, int target, int tid)
{
  __syncthreads();
  if (tid == 0) {
    __threadfence();
    __hip_atomic_fetch_add(cnt, 1, __ATOMIC_RELEASE, __HIP_MEMORY_SCOPE_AGENT);
    while (__hip_atomic_load(cnt, __ATOMIC_ACQUIRE, __HIP_MEMORY_SCOPE_AGENT) < target)
      __builtin_amdgcn_s_sleep(2);
    __threadfence();
  }
  __syncthreads();
}

enum EpiKind { EPI_PU=0, EPI_G2=1, EPI_G3=2, EPI_G4=3, EPI_HK=4 };

// 64x64 tile of C[m,n] = sum_k A[m,k]*B[n,k], both bf16 K-contiguous.
// 4 waves 2x2, wave tile 32x32 (WMT=WNT=2 -> 8 MFMA / K-iter / wave),
// 16x16x32 bf16 MFMA, BK=64, double-buffered LDS (stride 72 -> 2-way-only
// bank aliasing, free per m136). Pure uint4 staging (operands pre-cvt bf16).
template<int EK>
__device__ __forceinline__ void gemm_tile(const __hip_bfloat16* __restrict__ A,
    const __hip_bfloat16* __restrict__ Bw, int K, int T, int N, int bm, int bn,
    ushort_t (&sA)[2][4608], ushort_t (&sB)[2][4608], const P& p, int tid)
{
  constexpr int SA = 72;
  const int wave = tid >> 6, lane = tid & 63;
  const int wm = wave >> 1, wn = wave & 1;
  const int r = lane & 15, q = lane >> 4;
  const int row0 = tid >> 3;          // rows 0..31 (c=0) / +32 (c=1)
  const int kk0  = (tid * 8) & 63;

  uint4 ua[2], ub[2];
  auto loadT = [&](int k0) {
    #pragma unroll
    for (int c=0;c<2;++c)
      ua[c] = *reinterpret_cast<const uint4*>(A + (size_t)(bm+row0+c*32)*K + k0 + kk0);
    #pragma unroll
    for (int c=0;c<2;++c)
      ub[c] = *reinterpret_cast<const uint4*>(Bw + (size_t)(bn+row0+c*32)*K + k0 + kk0);
  };
  auto writeT = [&](int buf) {
    #pragma unroll
    for (int c=0;c<2;++c)
      *reinterpret_cast<uint4*>(&sA[buf][(row0+c*32)*SA + kk0]) = ua[c];
    #pragma unroll
    for (int c=0;c<2;++c)
      *reinterpret_cast<uint4*>(&sB[buf][(row0+c*32)*SA + kk0]) = ub[c];
  };

  f32x4 acc[2][2];
  #pragma unroll
  for (int i=0;i<2;++i)
    #pragma unroll
    for (int j=0;j<2;++j) acc[i][j] = (f32x4){0.f,0.f,0.f,0.f};

  loadT(0);
  writeT(0);
  for (int t=0; t<T; ++t) {
    __syncthreads();
    const int cur = t & 1;
    if (t+1 < T) loadT((t+1)*64);     // overlaps MFMA below
    #pragma unroll
    for (int ks=0; ks<2; ++ks) {
      bf16x8 af[2], bfr[2];
      #pragma unroll
      for (int mt=0; mt<2; ++mt)
        af[mt] = *reinterpret_cast<const bf16x8*>(&sA[cur][(wm*32+mt*16+r)*SA + ks*32 + q*8]);
      #pragma unroll
      for (int nt=0; nt<2; ++nt)
        bfr[nt] = *reinterpret_cast<const bf16x8*>(&sB[cur][(wn*32+nt*16+r)*SA + ks*32 + q*8]);
      #pragma unroll
      for (int mt=0; mt<2; ++mt)
        #pragma unroll
        for (int nt=0; nt<2; ++nt)
          acc[mt][nt] = __builtin_amdgcn_mfma_f32_16x16x32_bf16(af[mt], bfr[nt], acc[mt][nt], 0,0,0);
    }
    if (t+1 < T) writeT(cur ^ 1);
  }
  __syncthreads();   // protect LDS before this block's next job

  #pragma unroll
  for (int mt=0; mt<2; ++mt) {
    #pragma unroll
    for (int nt=0; nt<2; ++nt) {
      #pragma unroll
      for (int i=0;i<4;++i) {
        int grow = bm + wm*32 + mt*16 + q*4 + i;
        int gcol = bn + wn*32 + nt*16 + r;
        float v = acc[mt][nt][i];
        if constexpr (EK == EPI_PU) {
          p.Pu[(size_t)grow*DM + gcol] = f2bf(v + p.b_in[gcol]);
        } else if constexpr (EK == EPI_G2) {
          if (gcol < DI) {
            float xc = v * p.conv_w[gcol*DC + (DC-1)] + p.conv_b[gcol];
            p.Xs[(size_t)grow*DI + gcol] = f2bf(siluf_(xc));
          } else {
            p.Sz[(size_t)grow*DI + (gcol - DI)] = f2bf(siluf_(v));
          }
        } else if constexpr (EK == EPI_G3) {
          if (gcol < DTR) p.Acat[grow*128 + gcol] = f2bf(v);     // dt_r
          else            p.Xdbl[grow*128 + (gcol - DTR)] = v;   // B,C f32
        } else if constexpr (EK == EPI_G4) {
          float dt  = softplusf_(v + p.dt_bias[gcol]);
          float xsv = bf2f(p.Xs[(size_t)grow*DI + gcol]);
          float szv = bf2f(p.Sz[(size_t)grow*DI + gcol]);
          float y = (dt * xsv * p.bc[grow] + p.D_skip[gcol] * xsv) * szv;
          p.Yb[(size_t)grow*DI + gcol] = f2bf(y);
        } else { // EPI_HK
          p.out_hk[(size_t)grow*DM + gcol] = v;
        }
      }
    }
  }
}

__device__ __forceinline__ void cvt_arr(const float* __restrict__ src,
                                        __hip_bfloat16* __restrict__ dst,
                                        int n, int gtid, int gsz)
{
  for (int i = gtid*4; i < n; i += gsz*4) {
    float4 v = *reinterpret_cast<const float4*>(src + i);
    *reinterpret_cast<uint2*>(dst + i) = pack4(v);
  }
}

__device__ __forceinline__ void route(float t, const float* rW, const float* rb,
                                      float* w, float* mask, float* wn)
{
  float l[E_];
  float m = -1e30f;
  for (int e=0;e<E_;++e){ l[e] = t*rW[e] + rb[e]; m = fmaxf(m, l[e]); }
  float s = 0.f;
  for (int e=0;e<E_;++e){ w[e] = expf(l[e]-m); s += w[e]; }
  for (int e=0;e<E_;++e) w[e] /= s;
  int i1 = 0;
  for (int e=1;e<E_;++e) if (w[e] > w[i1]) i1 = e;
  int i2 = -1;
  for (int e=0;e<E_;++e) if (e != i1 && (i2 < 0 || w[e] > w[i2])) i2 = e;
  float ssel = w[i1] + w[i2] + 1e-8f;
  for (int e=0;e<E_;++e){
    float mk = (e==i1 || e==i2) ? 1.f : 0.f;
    mask[e] = mk;
    wn[e] = mk * w[e] / ssel;
  }
}

// routing + sin-embedding + kan delta for batch row b; dphi = 512-float LDS.
__device__ __forceinline__ void mote_inline(const P& p, int b, int tid, float* dphi)
{
  if (tid < 64) {
    float t  = p.tk_c[b];
    float tp = p.tk_p[b];
    float w_c[E_], mask_c[E_], wn_c[E_];
    float w_p[E_], mask_p[E_], wn_p[E_];
    route(t,  p.rW, p.rb, w_c, mask_c, wn_c);
    route(tp, p.rW, p.rb, w_p, mask_p, wn_p);
    if (tid < E_) {
      p.out_w[b*E_ + tid]    = w_c[tid];
      p.out_mask[b*E_ + tid] = mask_c[tid];
    }
    float ec = 0.f, epv = 0.f;
    #pragma unroll
    for (int e=0;e<E_;++e) {
      float f  = p.freq[e*DT + tid];
      float ph = p.phase[e*DT + tid];
      ec  += wn_c[e] * sinf(t*f + ph);
      epv += wn_p[e] * sinf(tp*f + ph);
    }
    const float h = 2.f/(G_-1);
    #pragma unroll
    for (int g=0; g<G_; ++g) {
      float gr = -1.f + g*h;
      float a  = (ec - gr)/h;
      float bb = (epv - gr)/h;
      dphi[tid*G_ + g] = expf(-a*a) - expf(-bb*bb);
    }
  }
  __syncthreads();
  if (tid < 64) {
    float accv = 0.f;
    const float* kwrow = p.kanW + tid*DT*G_;
    for (int j=0;j<DT*G_;++j) accv += dphi[j] * kwrow[j];
    p.Acat[b*128 + 64 + tid] = f2bf(accv);
  }
  __syncthreads();   // protect dphi for next loop iteration
}

__global__ __launch_bounds__(256, 4)
void mega_kernel(P p)
{
  __shared__ ushort_t sA[2][4608];
  __shared__ ushort_t sB[2][4608];
  __shared__ float scr[512];
  const int tid = threadIdx.x;
  const int bid = blockIdx.x;
  const int G = gridDim.x;
  const int gtid = bid*256 + tid, gsz = G*256;

  // ---- stage 0: f32->bf16 weight/activation conversion + mote ----
  cvt_arr(p.uk,       p.ukb,   B_*DM,      gtid, gsz);
  cvt_arr(p.W_in,     p.Winb,  DM*DM,      gtid, gsz);
  cvt_arr(p.W_inproj, p.Wipb,  2*DI*DM,    gtid, gsz);
  cvt_arr(p.W_x,      p.Wxb,   192*DI,     gtid, gsz);
  cvt_arr(p.W_out,    p.Woutb, DM*DI,      gtid, gsz);
  // Wcat[n,0:64]=W_dt[n], Wcat[n,64:128]=W_delta[n]
  for (int i = gtid*4; i < DI*64; i += gsz*4) {
    int nrow = i >> 6, j = i & 63;
    float4 a = *reinterpret_cast<const float4*>(p.W_dt + i);
    float4 b = *reinterpret_cast<const float4*>(p.W_delta + i);
    *reinterpret_cast<uint2*>(p.Wcat + nrow*128 + j)      = pack4(a);
    *reinterpret_cast<uint2*>(p.Wcat + nrow*128 + 64 + j) = pack4(b);
  }
  for (int b = bid; b < B_; b += G)
    mote_inline(p, b, tid, scr);
  gsync(p.bar+0, G, tid);

  // ---- G1: pu = uk @ W_in^T + b_in (512x1024x1024), 128 jobs ----
  for (int job = bid; job < 128; job += G) {
    int my = job >> 4, nx = job & 15;
    gemm_tile<EPI_PU>(p.ukb, p.Winb, DM, 16, DM, my*64, nx*64, sA, sB, p, tid);
  }
  gsync(p.bar+1, G, tid);

  // ---- G2: xz = pu @ W_inproj^T (512x4096x1024), 512 jobs, fused conv/silu ----
  for (int job = bid; job < 512; job += G) {
    int my = job >> 6, nx = job & 63;
    gemm_tile<EPI_G2>(p.Pu, p.Wipb, DM, 16, 2*DI, my*64, nx*64, sA, sB, p, tid);
  }
  gsync(p.bar+2, G, tid);

  // ---- G3: x_dbl = xs @ W_x^T (512x192x2048), 24 jobs ----
  for (int job = bid; job < 24; job += G) {
    int my = job / 3, nx = job % 3;
    gemm_tile<EPI_G3>(p.Xs, p.Wxb, DI, 32, 192, my*64, nx*64, sA, sB, p, tid);
  }
  gsync(p.bar+3, G, tid);

  // ---- bc[r] = dot(B_r, C_r)  (factorized einsum('bds,bs->bd')) ----
  for (int row = bid; row < B_; row += G) {
    if (tid < 64) {
      float pv = p.Xdbl[row*128 + tid] * p.Xdbl[row*128 + 64 + tid];
      #pragma unroll
      for (int off=32; off; off>>=1) pv += __shfl_down(pv, off);
      if (tid == 0) p.bc[row] = pv;
    }
  }
  gsync(p.bar+4, G, tid);

  // ---- G4: dt GEMM (512x2048x128, B=[W_dt|W_delta]) + softplus + y, 256 jobs ----
  for (int job = bid; job < 256; job += G) {
    int my = job >> 5, nx = job & 31;
    gemm_tile<EPI_G4>(p.Acat, p.Wcat, 128, 2, DI, my*64, nx*64, sA, sB, p, tid);
  }
  gsync(p.bar+5, G, tid);

  // ---- G5: hk = y @ W_out^T (512x1024x2048), 128 jobs -> f32 out ----
  for (int job = bid; job < 128; job += G) {
    int my = job >> 4, nx = job & 15;
    gemm_tile<EPI_HK>(p.Yb, p.Woutb, DI, 32, DM, my*64, nx*64, sA, sB, p, tid);
  }
}

extern "C" void kernel_launch(void* const* d_in, const int* in_sizes, int n_in,
                              void* d_out, int out_size, void* d_ws, size_t ws_size,
                              hipStream_t stream)
{
  char* ws = (char*)d_ws;
  P p;
  p.uk      = (const float*)d_in[0];
  p.tk_c    = (const float*)d_in[1];
  p.tk_p    = (const float*)d_in[2];
  p.W_in    = (const float*)d_in[3];
  p.b_in    = (const float*)d_in[4];
  p.rW      = (const float*)d_in[5];
  p.rb      = (const float*)d_in[6];
  p.freq    = (const float*)d_in[7];
  p.phase   = (const float*)d_in[8];
  p.kanW    = (const float*)d_in[9];
  p.W_inproj= (const float*)d_in[10];
  p.conv_w  = (const float*)d_in[11];
  p.conv_b  = (const float*)d_in[12];
  p.W_x     = (const float*)d_in[13];
  p.W_dt    = (const float*)d_in[14];
  p.dt_bias = (const float*)d_in[15];
  p.W_delta = (const float*)d_in[16];
  /* d_in[17] = A_log — dead in the reference math */
  p.D_skip  = (const float*)d_in[18];
  p.W_out   = (const float*)d_in[19];

  const size_t MB = 1 << 20;
  p.ukb   = (__hip_bfloat16*)(ws + 0*MB);            // 1 MB
  p.Pu    = (__hip_bfloat16*)(ws + 1*MB);            // 1 MB
  p.Xs    = (__hip_bfloat16*)(ws + 2*MB);            // 2 MB
  p.Sz    = (__hip_bfloat16*)(ws + 4*MB);            // 2 MB
  p.Yb    = (__hip_bfloat16*)(ws + 6*MB);            // 2 MB
  p.Acat  = (__hip_bfloat16*)(ws + 8*MB);            // 128 KB
  p.Xdbl  = (float*)         (ws + 8*MB + (256<<10));// 256 KB
  p.bc    = (float*)         (ws + 8*MB + (512<<10));// 2 KB
  p.bar   = (int*)           (ws + 8*MB + (768<<10));// 64 B
  p.Winb  = (__hip_bfloat16*)(ws + 9*MB);            // 2 MB
  p.Wipb  = (__hip_bfloat16*)(ws + 11*MB);           // 8 MB
  p.Wxb   = (__hip_bfloat16*)(ws + 19*MB);           // 0.75 MB
  p.Woutb = (__hip_bfloat16*)(ws + 20*MB);           // 4 MB
  p.Wcat  = (__hip_bfloat16*)(ws + 24*MB);           // 0.5 MB

  p.out_hk   = (float*)d_out;
  p.out_w    = p.out_hk + (size_t)B_*DM;
  p.out_mask = p.out_w  + (size_t)B_*E_;

  hipMemsetAsync(p.bar, 0, 64, stream);
  mega_kernel<<<dim3(GRID), dim3(256), 0, stream>>>(p);
}

// Round 7
// 1131.033 us; speedup vs baseline: 1.2286x; 1.2286x over previous
//
#include <hip/hip_runtime.h>
#include <hip/hip_bf16.h>
#include <math.h>

#define B_  512
#define DM  1024
#define DI  2048
#define DS  64
#define DTR 64
#define DT  64
#define G_  8
#define E_  4
#define DC  4
#define GRID 768

typedef __bf16 bf16x8 __attribute__((ext_vector_type(8)));
typedef float  f32x4  __attribute__((ext_vector_type(4)));
typedef unsigned short ushort_t;

__device__ __forceinline__ float bf2f(__hip_bfloat16 h) { return __bfloat162float(h); }
__device__ __forceinline__ __hip_bfloat16 f2bf(float f) { return __float2bfloat16(f); }
__device__ __forceinline__ float sigmoidf_(float x){ return 1.f/(1.f+expf(-x)); }
__device__ __forceinline__ float siluf_(float x){ return x*sigmoidf_(x); }
__device__ __forceinline__ float softplusf_(float x){ return (x>20.f)? x : log1pf(expf(x)); }

__device__ __forceinline__ unsigned int pack2(float a, float b) {
  unsigned short ua = __builtin_bit_cast(unsigned short, (__bf16)a);
  unsigned short ub = __builtin_bit_cast(unsigned short, (__bf16)b);
  return (unsigned int)ua | ((unsigned int)ub << 16);
}
__device__ __forceinline__ uint2 pack4(float4 v) {
  uint2 o; o.x = pack2(v.x, v.y); o.y = pack2(v.z, v.w); return o;
}

struct P {
  const float *uk, *W_in, *b_in, *tk_c, *tk_p, *rW, *rb, *freq, *phase, *kanW;
  const float *W_inproj, *conv_w, *conv_b, *W_x, *W_dt, *dt_bias, *W_delta, *D_skip, *W_out;
  __hip_bfloat16 *ukb, *Winb, *Wipb, *Wxb, *Woutb, *Wcat;   // stage-0 bf16 copies
  __hip_bfloat16 *Pu, *Xs, *Sz, *Yb, *Acat;
  float *PartA, *PartB;        // split-K partials (aliased into Xs/Sz resp. Yb)
  float *bc;
  int *bar;
  float *out_hk, *out_w, *out_mask;
};

// Software grid barrier. Residency-safe: LDS 29.7KB -> 5 blk/CU,
// launch_bounds(256,4) -> VGPR<=128 -> 4 blk/CU; capacity 1024 >= grid 768.
// Poll with long s_sleep: round-6 post-mortem showed ~650 idle blocks polling
// one LLC line every ~128cy saturated the coherence path and slowed workers
// ~5x. s_sleep(64) (~1.7us) cuts poll traffic ~30x; overshoot ~<=1us/barrier.
__device__ __forceinline__ void gsync(int* cnt, int target, int tid)
{
  __syncthreads();
  if (tid == 0) {
    __threadfence();
    __hip_atomic_fetch_add(cnt, 1, __ATOMIC_RELEASE, __HIP_MEMORY_SCOPE_AGENT);
    int probes = 0;
    while (__hip_atomic_load(cnt, __ATOMIC_ACQUIRE, __HIP_MEMORY_SCOPE_AGENT) < target) {
      if (probes < 2) { __builtin_amdgcn_s_sleep(8);  ++probes; }
      else            { __builtin_amdgcn_s_sleep(64); }
    }
    __threadfence();
  }
  __syncthreads();
}

enum EpiKind { EPI_PART=0, EPI_G2=1, EPI_G4=2 };

// 32x64 tile of C[m,n] = sum_k A[m,k]*B[n,k], both bf16 K-contiguous, equal
// K-stride. 4 waves 2x2 (wave tile 16x32), 16x16x32 bf16 MFMA, BK=64,
// double-buffered LDS (stride 72 -> 2-way-only bank aliasing, free per m136).
// Pure uint4 staging (operands pre-converted to bf16 in stage 0).
template<int EK>
__device__ __forceinline__ void gemm_tile(const __hip_bfloat16* __restrict__ A,
    const __hip_bfloat16* __restrict__ Bw, int K, int kBase, int T, int N,
    int bm, int bn, float* __restrict__ partPtr,
    ushort_t (&sA)[2][2304], ushort_t (&sB)[2][4608], const P& p, int tid)
{
  constexpr int SA = 72;
  const int wave = tid >> 6, lane = tid & 63;
  const int wm = wave >> 1, wn = wave & 1;
  const int r = lane & 15, q = lane >> 4;
  const int row0 = tid >> 3;          // 0..31
  const int kk0  = (tid * 8) & 63;

  uint4 ua, ub[2];
  auto loadT = [&](int k0) {
    ua = *reinterpret_cast<const uint4*>(A + (size_t)(bm+row0)*K + k0 + kk0);
    #pragma unroll
    for (int c=0;c<2;++c)
      ub[c] = *reinterpret_cast<const uint4*>(Bw + (size_t)(bn+row0+c*32)*K + k0 + kk0);
  };
  auto writeT = [&](int buf) {
    *reinterpret_cast<uint4*>(&sA[buf][row0*SA + kk0]) = ua;
    #pragma unroll
    for (int c=0;c<2;++c)
      *reinterpret_cast<uint4*>(&sB[buf][(row0+c*32)*SA + kk0]) = ub[c];
  };

  f32x4 acc[2];
  #pragma unroll
  for (int j=0;j<2;++j) acc[j] = (f32x4){0.f,0.f,0.f,0.f};

  loadT(kBase);
  writeT(0);
  for (int t=0; t<T; ++t) {
    __syncthreads();
    const int cur = t & 1;
    if (t+1 < T) loadT(kBase + (t+1)*64);   // overlaps MFMA below
    #pragma unroll
    for (int ks=0; ks<2; ++ks) {
      bf16x8 af = *reinterpret_cast<const bf16x8*>(&sA[cur][(wm*16+r)*SA + ks*32 + q*8]);
      bf16x8 bfr[2];
      #pragma unroll
      for (int nt=0; nt<2; ++nt)
        bfr[nt] = *reinterpret_cast<const bf16x8*>(&sB[cur][(wn*32+nt*16+r)*SA + ks*32 + q*8]);
      #pragma unroll
      for (int nt=0; nt<2; ++nt)
        acc[nt] = __builtin_amdgcn_mfma_f32_16x16x32_bf16(af, bfr[nt], acc[nt], 0,0,0);
    }
    if (t+1 < T) writeT(cur ^ 1);
  }
  __syncthreads();   // protect LDS before this block's next job

  #pragma unroll
  for (int nt=0; nt<2; ++nt) {
    #pragma unroll
    for (int i=0;i<4;++i) {
      int grow = bm + wm*16 + q*4 + i;
      int gcol = bn + wn*32 + nt*16 + r;
      float v = acc[nt][i];
      if constexpr (EK == EPI_PART) {
        partPtr[(size_t)grow*N + gcol] = v;
      } else if constexpr (EK == EPI_G2) {
        if (gcol < DI) {
          float xc = v * p.conv_w[gcol*DC + (DC-1)] + p.conv_b[gcol];
          p.Xs[(size_t)grow*DI + gcol] = f2bf(siluf_(xc));
        } else {
          p.Sz[(size_t)grow*DI + (gcol - DI)] = f2bf(siluf_(v));
        }
      } else { // EPI_G4
        float dt  = softplusf_(v + p.dt_bias[gcol]);
        float xsv = bf2f(p.Xs[(size_t)grow*DI + gcol]);
        float szv = bf2f(p.Sz[(size_t)grow*DI + gcol]);
        float y = (dt * xsv * p.bc[grow] + p.D_skip[gcol] * xsv) * szv;
        p.Yb[(size_t)grow*DI + gcol] = f2bf(y);
      }
    }
  }
}

__device__ __forceinline__ void cvt_arr(const float* __restrict__ src,
                                        __hip_bfloat16* __restrict__ dst,
                                        int n, int gtid, int gsz)
{
  for (int i = gtid*4; i < n; i += gsz*4) {
    float4 v = *reinterpret_cast<const float4*>(src + i);
    *reinterpret_cast<uint2*>(dst + i) = pack4(v);
  }
}

__device__ __forceinline__ void route(float t, const float* rW, const float* rb,
                                      float* w, float* mask, float* wn)
{
  float l[E_];
  float m = -1e30f;
  for (int e=0;e<E_;++e){ l[e] = t*rW[e] + rb[e]; m = fmaxf(m, l[e]); }
  float s = 0.f;
  for (int e=0;e<E_;++e){ w[e] = expf(l[e]-m); s += w[e]; }
  for (int e=0;e<E_;++e) w[e] /= s;
  int i1 = 0;
  for (int e=1;e<E_;++e) if (w[e] > w[i1]) i1 = e;
  int i2 = -1;
  for (int e=0;e<E_;++e) if (e != i1 && (i2 < 0 || w[e] > w[i2])) i2 = e;
  float ssel = w[i1] + w[i2] + 1e-8f;
  for (int e=0;e<E_;++e){
    float mk = (e==i1 || e==i2) ? 1.f : 0.f;
    mask[e] = mk;
    wn[e] = mk * w[e] / ssel;
  }
}

// routing + sin-embedding + kan delta for batch row b; dphi = 512-float LDS.
__device__ __forceinline__ void mote_inline(const P& p, int b, int tid, float* dphi)
{
  if (tid < 64) {
    float t  = p.tk_c[b];
    float tp = p.tk_p[b];
    float w_c[E_], mask_c[E_], wn_c[E_];
    float w_p[E_], mask_p[E_], wn_p[E_];
    route(t,  p.rW, p.rb, w_c, mask_c, wn_c);
    route(tp, p.rW, p.rb, w_p, mask_p, wn_p);
    if (tid < E_) {
      p.out_w[b*E_ + tid]    = w_c[tid];
      p.out_mask[b*E_ + tid] = mask_c[tid];
    }
    float ec = 0.f, epv = 0.f;
    #pragma unroll
    for (int e=0;e<E_;++e) {
      float f  = p.freq[e*DT + tid];
      float ph = p.phase[e*DT + tid];
      ec  += wn_c[e] * sinf(t*f + ph);
      epv += wn_p[e] * sinf(tp*f + ph);
    }
    const float h = 2.f/(G_-1);
    #pragma unroll
    for (int g=0; g<G_; ++g) {
      float gr = -1.f + g*h;
      float a  = (ec - gr)/h;
      float bb = (epv - gr)/h;
      dphi[tid*G_ + g] = expf(-a*a) - expf(-bb*bb);
    }
  }
  __syncthreads();
  if (tid < 64) {
    float accv = 0.f;
    const float* kwrow = p.kanW + tid*DT*G_;
    for (int j=0;j<DT*G_;++j) accv += dphi[j] * kwrow[j];
    p.Acat[b*128 + 64 + tid] = f2bf(accv);
  }
  __syncthreads();   // protect dphi across loop iterations
}

__global__ __launch_bounds__(256, 4)
void mega_kernel(P p)
{
  __shared__ ushort_t sA[2][2304];
  __shared__ ushort_t sB[2][4608];
  __shared__ float scr[512];
  const int tid = threadIdx.x;
  const int bid = blockIdx.x;
  const int G = gridDim.x;
  const int gtid = bid*256 + tid, gsz = G*256;

  // ---- stage 0: f32->bf16 conversions + mote (all blocks busy) ----
  cvt_arr(p.uk,       p.ukb,   B_*DM,   gtid, gsz);
  cvt_arr(p.W_in,     p.Winb,  DM*DM,   gtid, gsz);
  cvt_arr(p.W_inproj, p.Wipb,  2*DI*DM, gtid, gsz);
  cvt_arr(p.W_x,      p.Wxb,   192*DI,  gtid, gsz);
  cvt_arr(p.W_out,    p.Woutb, DM*DI,   gtid, gsz);
  for (int i = gtid*4; i < DI*64; i += gsz*4) {   // Wcat = [W_dt | W_delta]
    int nrow = i >> 6, j = i & 63;
    float4 a = *reinterpret_cast<const float4*>(p.W_dt + i);
    float4 b = *reinterpret_cast<const float4*>(p.W_delta + i);
    *reinterpret_cast<uint2*>(p.Wcat + nrow*128 + j)      = pack4(a);
    *reinterpret_cast<uint2*>(p.Wcat + nrow*128 + 64 + j) = pack4(b);
  }
  for (int b = bid; b < B_; b += G)
    mote_inline(p, b, tid, scr);
  gsync(p.bar+0, G, tid);

  // ---- G1: pu partials, split-K x2 (512 jobs, K-chunk 512, T=8) ----
  for (int job = bid; job < 512; job += G) {
    int z = job >> 8, rem = job & 255;
    int my = rem >> 4, nx = rem & 15;
    gemm_tile<EPI_PART>(p.ukb, p.Winb, DM, z*512, 8, DM, my*32, nx*64,
                        p.PartA + (size_t)z*B_*DM, sA, sB, p, tid);
  }
  gsync(p.bar+1, G, tid);

  // ---- R1: Pu = bf16(sum partials + b_in) ----
  for (int i = gtid*4; i < B_*DM; i += gsz*4) {
    float4 s0 = *reinterpret_cast<const float4*>(p.PartA + i);
    float4 s1 = *reinterpret_cast<const float4*>(p.PartA + B_*DM + i);
    float4 bv = *reinterpret_cast<const float4*>(p.b_in + (i & (DM-1)));
    float4 s; s.x=s0.x+s1.x+bv.x; s.y=s0.y+s1.y+bv.y; s.z=s0.z+s1.z+bv.z; s.w=s0.w+s1.w+bv.w;
    *reinterpret_cast<uint2*>(p.Pu + i) = pack4(s);
  }
  gsync(p.bar+2, G, tid);

  // ---- G2: xz = pu @ W_inproj^T (1024 jobs, K=1024, T=16), fused conv/silu ----
  for (int job = bid; job < 1024; job += G) {
    int my = job >> 6, nx = job & 63;
    gemm_tile<EPI_G2>(p.Pu, p.Wipb, DM, 0, 16, 2*DI, my*32, nx*64,
                      nullptr, sA, sB, p, tid);
  }
  gsync(p.bar+3, G, tid);

  // ---- G3: x_dbl partials, split-K x4 (192 jobs, K-chunk 512, T=8) ----
  for (int job = bid; job < 192; job += G) {
    int z = job / 48, rem = job % 48;
    int my = rem / 3, nx = rem % 3;
    gemm_tile<EPI_PART>(p.Xs, p.Wxb, DI, z*512, 8, 192, my*32, nx*64,
                        p.PartB + (size_t)z*B_*192, sA, sB, p, tid);
  }
  gsync(p.bar+4, G, tid);

  // ---- R3: reduce x_dbl -> Acat[:,0:64] (dt_r) + bc = dot(B_r,C_r) ----
  for (int row = bid; row < B_; row += G) {
    __syncthreads();
    float s = 0.f;
    if (tid < 192) {
      #pragma unroll
      for (int z=0; z<4; ++z) s += p.PartB[(size_t)z*B_*192 + (size_t)row*192 + tid];
      if (tid < 64) p.Acat[row*128 + tid] = f2bf(s);
      else          scr[tid - 64] = s;
    }
    __syncthreads();
    if (tid < 64) {
      float pv = scr[tid] * scr[tid + 64];
      #pragma unroll
      for (int off=32; off; off>>=1) pv += __shfl_down(pv, off);
      if (tid == 0) p.bc[row] = pv;
    }
  }
  gsync(p.bar+5, G, tid);

  // ---- G4: dt GEMM + softplus + y-fusion (512 jobs, K=128, T=2) ----
  for (int job = bid; job < 512; job += G) {
    int my = job >> 5, nx = job & 31;
    gemm_tile<EPI_G4>(p.Acat, p.Wcat, 128, 0, 2, DI, my*32, nx*64,
                      nullptr, sA, sB, p, tid);
  }
  gsync(p.bar+6, G, tid);

  // ---- G5: hk partials, split-K x2 (512 jobs, K-chunk 1024, T=16) ----
  for (int job = bid; job < 512; job += G) {
    int z = job >> 8, rem = job & 255;
    int my = rem >> 4, nx = rem & 15;
    gemm_tile<EPI_PART>(p.Yb, p.Woutb, DI, z*1024, 16, DM, my*32, nx*64,
                        p.PartA + (size_t)z*B_*DM, sA, sB, p, tid);
  }
  gsync(p.bar+7, G, tid);

  // ---- R5: hk = sum partials (f32 out) ----
  for (int i = gtid*4; i < B_*DM; i += gsz*4) {
    float4 s0 = *reinterpret_cast<const float4*>(p.PartA + i);
    float4 s1 = *reinterpret_cast<const float4*>(p.PartA + B_*DM + i);
    float4 s; s.x=s0.x+s1.x; s.y=s0.y+s1.y; s.z=s0.z+s1.z; s.w=s0.w+s1.w;
    *reinterpret_cast<float4*>(p.out_hk + i) = s;
  }
}

extern "C" void kernel_launch(void* const* d_in, const int* in_sizes, int n_in,
                              void* d_out, int out_size, void* d_ws, size_t ws_size,
                              hipStream_t stream)
{
  char* ws = (char*)d_ws;
  P p;
  p.uk      = (const float*)d_in[0];
  p.tk_c    = (const float*)d_in[1];
  p.tk_p    = (const float*)d_in[2];
  p.W_in    = (const float*)d_in[3];
  p.b_in    = (const float*)d_in[4];
  p.rW      = (const float*)d_in[5];
  p.rb      = (const float*)d_in[6];
  p.freq    = (const float*)d_in[7];
  p.phase   = (const float*)d_in[8];
  p.kanW    = (const float*)d_in[9];
  p.W_inproj= (const float*)d_in[10];
  p.conv_w  = (const float*)d_in[11];
  p.conv_b  = (const float*)d_in[12];
  p.W_x     = (const float*)d_in[13];
  p.W_dt    = (const float*)d_in[14];
  p.dt_bias = (const float*)d_in[15];
  p.W_delta = (const float*)d_in[16];
  /* d_in[17] = A_log — dead in the reference math */
  p.D_skip  = (const float*)d_in[18];
  p.W_out   = (const float*)d_in[19];

  const size_t MB = 1 << 20;
  p.ukb   = (__hip_bfloat16*)(ws + 0*MB);            // 1 MB
  p.Pu    = (__hip_bfloat16*)(ws + 1*MB);            // 1 MB
  p.Xs    = (__hip_bfloat16*)(ws + 2*MB);            // 2 MB
  p.Sz    = (__hip_bfloat16*)(ws + 4*MB);            // 2 MB
  p.Yb    = (__hip_bfloat16*)(ws + 6*MB);            // 2 MB
  p.Acat  = (__hip_bfloat16*)(ws + 8*MB);            // 128 KB
  p.bc    = (float*)         (ws + 8*MB + (256<<10));// 2 KB
  p.bar   = (int*)           (ws + 8*MB + (512<<10));// 64 B
  p.Winb  = (__hip_bfloat16*)(ws + 9*MB);            // 2 MB
  p.Wipb  = (__hip_bfloat16*)(ws + 11*MB);           // 8 MB
  p.Wxb   = (__hip_bfloat16*)(ws + 19*MB);           // 0.75 MB
  p.Woutb = (__hip_bfloat16*)(ws + 20*MB);           // 4 MB
  p.Wcat  = (__hip_bfloat16*)(ws + 24*MB);           // 0.5 MB
  // Partials aliased into barrier-separated dead phases:
  //  PartA (4 MB) = Xs..Sz region: G1 partials (before G2 writes Xs/Sz) and
  //  G5 partials (after G4's epilogue last reads Xs/Sz).
  //  PartB (1.5 MB) = Yb region: G3 partials (before G4 writes Yb).
  p.PartA = (float*)(ws + 2*MB);
  p.PartB = (float*)(ws + 6*MB);

  p.out_hk   = (float*)d_out;
  p.out_w    = p.out_hk + (size_t)B_*DM;
  p.out_mask = p.out_w  + (size_t)B_*E_;

  hipMemsetAsync(p.bar, 0, 64, stream);
  mega_kernel<<<dim3(GRID), dim3(256), 0, stream>>>(p);
}

// Round 8
// 186.312 us; speedup vs baseline: 7.4582x; 6.0707x over previous
//
#include <hip/hip_runtime.h>
#include <hip/hip_bf16.h>
#include <math.h>

#define B_  512
#define DM  1024
#define DI  2048
#define DS  64
#define DTR 64
#define DT  64
#define G_  8
#define E_  4
#define DC  4

typedef __bf16 bf16x8 __attribute__((ext_vector_type(8)));
typedef float  f32x4  __attribute__((ext_vector_type(4)));
typedef unsigned short ushort_t;

__device__ __forceinline__ float bf2f(__hip_bfloat16 h) { return __bfloat162float(h); }
__device__ __forceinline__ __hip_bfloat16 f2bf(float f) { return __float2bfloat16(f); }
__device__ __forceinline__ float sigmoidf_(float x){ return 1.f/(1.f+expf(-x)); }
__device__ __forceinline__ float siluf_(float x){ return x*sigmoidf_(x); }
__device__ __forceinline__ float softplusf_(float x){ return (x>20.f)? x : log1pf(expf(x)); }

__device__ __forceinline__ unsigned int pack2(float a, float b) {
  unsigned short ua = __builtin_bit_cast(unsigned short, (__bf16)a);
  unsigned short ub = __builtin_bit_cast(unsigned short, (__bf16)b);
  return (unsigned int)ua | ((unsigned int)ub << 16);
}
__device__ __forceinline__ uint2 pack4(float4 v) {
  uint2 o; o.x = pack2(v.x, v.y); o.y = pack2(v.z, v.w); return o;
}

struct P {
  const float *uk, *W_in, *b_in, *tk_c, *tk_p, *rW, *rb, *freq, *phase, *kanW;
  const float *W_inproj, *conv_w, *conv_b, *W_x, *W_dt, *dt_bias, *W_delta, *D_skip, *W_out;
  __hip_bfloat16 *ukb, *Winb, *Wipb, *Wxb, *Woutb, *Wcat;
  __hip_bfloat16 *Pu, *Xs, *Sz, *Yb, *Acat;
  float *PartA, *PartC;    // split-K partials (G1/G5 -> PartA, G3 -> PartC)
  float *bc;
  float *out_hk, *out_w, *out_mask;
};

enum EpiKind { EPI_PART=0, EPI_G2=1, EPI_G4=2 };

// 64x64 tile of C[m,n] = sum_k A[m,k]*B[n,k], both bf16, K-contiguous.
// 4 waves 2x2 (wave tile 32x32 -> 8 MFMA/K-iter/wave), 16x16x32 bf16 MFMA,
// BK=64, double-buffered LDS (stride 72 -> 2-way-only aliasing, free per m136),
// pure uint4 staging (operands pre-converted bf16 in prep).
template<int EK>
__device__ __forceinline__ void gemm_tile(const __hip_bfloat16* __restrict__ A,
    const __hip_bfloat16* __restrict__ Bw, int K, int kBase, int T, int N,
    int bm, int bn, float* __restrict__ partPtr,
    ushort_t (&sA)[2][4608], ushort_t (&sB)[2][4608], const P& p, int tid)
{
  constexpr int SA = 72;
  const int wave = tid >> 6, lane = tid & 63;
  const int wm = wave >> 1, wn = wave & 1;
  const int r = lane & 15, q = lane >> 4;
  const int row0 = tid >> 3;          // 0..31, +32 for c=1
  const int kk0  = (tid * 8) & 63;

  uint4 ua[2], ub[2];
  auto loadT = [&](int k0) {
    #pragma unroll
    for (int c=0;c<2;++c)
      ua[c] = *reinterpret_cast<const uint4*>(A + (size_t)(bm+row0+c*32)*K + k0 + kk0);
    #pragma unroll
    for (int c=0;c<2;++c)
      ub[c] = *reinterpret_cast<const uint4*>(Bw + (size_t)(bn+row0+c*32)*K + k0 + kk0);
  };
  auto writeT = [&](int buf) {
    #pragma unroll
    for (int c=0;c<2;++c)
      *reinterpret_cast<uint4*>(&sA[buf][(row0+c*32)*SA + kk0]) = ua[c];
    #pragma unroll
    for (int c=0;c<2;++c)
      *reinterpret_cast<uint4*>(&sB[buf][(row0+c*32)*SA + kk0]) = ub[c];
  };

  f32x4 acc[2][2];
  #pragma unroll
  for (int i=0;i<2;++i)
    #pragma unroll
    for (int j=0;j<2;++j) acc[i][j] = (f32x4){0.f,0.f,0.f,0.f};

  loadT(kBase);
  writeT(0);
  for (int t=0; t<T; ++t) {
    __syncthreads();
    const int cur = t & 1;
    if (t+1 < T) loadT(kBase + (t+1)*64);   // overlaps MFMA below
    #pragma unroll
    for (int ks=0; ks<2; ++ks) {
      bf16x8 af[2], bfr[2];
      #pragma unroll
      for (int mt=0; mt<2; ++mt)
        af[mt] = *reinterpret_cast<const bf16x8*>(&sA[cur][(wm*32+mt*16+r)*SA + ks*32 + q*8]);
      #pragma unroll
      for (int nt=0; nt<2; ++nt)
        bfr[nt] = *reinterpret_cast<const bf16x8*>(&sB[cur][(wn*32+nt*16+r)*SA + ks*32 + q*8]);
      #pragma unroll
      for (int mt=0; mt<2; ++mt)
        #pragma unroll
        for (int nt=0; nt<2; ++nt)
          acc[mt][nt] = __builtin_amdgcn_mfma_f32_16x16x32_bf16(af[mt], bfr[nt], acc[mt][nt], 0,0,0);
    }
    if (t+1 < T) writeT(cur ^ 1);
  }

  #pragma unroll
  for (int mt=0; mt<2; ++mt) {
    #pragma unroll
    for (int nt=0; nt<2; ++nt) {
      #pragma unroll
      for (int i=0;i<4;++i) {
        int grow = bm + wm*32 + mt*16 + q*4 + i;
        int gcol = bn + wn*32 + nt*16 + r;
        float v = acc[mt][nt][i];
        if constexpr (EK == EPI_PART) {
          partPtr[(size_t)grow*N + gcol] = v;
        } else if constexpr (EK == EPI_G2) {
          if (gcol < DI) {
            float xc = v * p.conv_w[gcol*DC + (DC-1)] + p.conv_b[gcol];
            p.Xs[(size_t)grow*DI + gcol] = f2bf(siluf_(xc));
          } else {
            p.Sz[(size_t)grow*DI + (gcol - DI)] = f2bf(siluf_(v));
          }
        } else { // EPI_G4
          float dt  = softplusf_(v + p.dt_bias[gcol]);
          float xsv = bf2f(p.Xs[(size_t)grow*DI + gcol]);
          float szv = bf2f(p.Sz[(size_t)grow*DI + gcol]);
          float y = (dt * xsv * p.bc[grow] + p.D_skip[gcol] * xsv) * szv;
          p.Yb[(size_t)grow*DI + gcol] = f2bf(y);
        }
      }
    }
  }
}

// ---- prep: all f32->bf16 conversions + mote routing/kan ----

__device__ __forceinline__ void cvt_arr(const float* __restrict__ src,
                                        __hip_bfloat16* __restrict__ dst,
                                        int n, int gtid, int gsz)
{
  for (int i = gtid*4; i < n; i += gsz*4) {
    float4 v = *reinterpret_cast<const float4*>(src + i);
    *reinterpret_cast<uint2*>(dst + i) = pack4(v);
  }
}

__device__ __forceinline__ void route(float t, const float* rW, const float* rb,
                                      float* w, float* mask, float* wn)
{
  float l[E_];
  float m = -1e30f;
  for (int e=0;e<E_;++e){ l[e] = t*rW[e] + rb[e]; m = fmaxf(m, l[e]); }
  float s = 0.f;
  for (int e=0;e<E_;++e){ w[e] = expf(l[e]-m); s += w[e]; }
  for (int e=0;e<E_;++e) w[e] /= s;
  int i1 = 0;
  for (int e=1;e<E_;++e) if (w[e] > w[i1]) i1 = e;
  int i2 = -1;
  for (int e=0;e<E_;++e) if (e != i1 && (i2 < 0 || w[e] > w[i2])) i2 = e;
  float ssel = w[i1] + w[i2] + 1e-8f;
  for (int e=0;e<E_;++e){
    float mk = (e==i1 || e==i2) ? 1.f : 0.f;
    mask[e] = mk;
    wn[e] = mk * w[e] / ssel;
  }
}

__global__ __launch_bounds__(256)
void prep_kernel(P p)
{
  __shared__ float dphi[512];
  const int tid = threadIdx.x, bid = blockIdx.x;
  const int gtid = bid*256 + tid, gsz = gridDim.x*256;

  cvt_arr(p.uk,       p.ukb,   B_*DM,   gtid, gsz);
  cvt_arr(p.W_in,     p.Winb,  DM*DM,   gtid, gsz);
  cvt_arr(p.W_inproj, p.Wipb,  2*DI*DM, gtid, gsz);
  cvt_arr(p.W_x,      p.Wxb,   192*DI,  gtid, gsz);
  cvt_arr(p.W_out,    p.Woutb, DM*DI,   gtid, gsz);
  for (int i = gtid*4; i < DI*64; i += gsz*4) {   // Wcat = [W_dt | W_delta]
    int nrow = i >> 6, j = i & 63;
    float4 a = *reinterpret_cast<const float4*>(p.W_dt + i);
    float4 b = *reinterpret_cast<const float4*>(p.W_delta + i);
    *reinterpret_cast<uint2*>(p.Wcat + nrow*128 + j)      = pack4(a);
    *reinterpret_cast<uint2*>(p.Wcat + nrow*128 + 64 + j) = pack4(b);
  }

  // mote for row b = bid (grid >= 512; only first 512 blocks)
  if (bid < B_) {
    const int b = bid;
    if (tid < 64) {
      float t  = p.tk_c[b];
      float tp = p.tk_p[b];
      float w_c[E_], mask_c[E_], wn_c[E_];
      float w_p[E_], mask_p[E_], wn_p[E_];
      route(t,  p.rW, p.rb, w_c, mask_c, wn_c);
      route(tp, p.rW, p.rb, w_p, mask_p, wn_p);
      if (tid < E_) {
        p.out_w[b*E_ + tid]    = w_c[tid];
        p.out_mask[b*E_ + tid] = mask_c[tid];
      }
      float ec = 0.f, epv = 0.f;
      #pragma unroll
      for (int e=0;e<E_;++e) {
        float f  = p.freq[e*DT + tid];
        float ph = p.phase[e*DT + tid];
        ec  += wn_c[e] * sinf(t*f + ph);
        epv += wn_p[e] * sinf(tp*f + ph);
      }
      const float h = 2.f/(G_-1);
      #pragma unroll
      for (int g=0; g<G_; ++g) {
        float gr = -1.f + g*h;
        float a  = (ec - gr)/h;
        float bb = (epv - gr)/h;
        dphi[tid*G_ + g] = expf(-a*a) - expf(-bb*bb);
      }
    }
    __syncthreads();
    if (tid < 64) {
      float accv = 0.f;
      const float* kwrow = p.kanW + tid*DT*G_;
      for (int j=0;j<DT*G_;++j) accv += dphi[j] * kwrow[j];
      p.Acat[b*128 + 64 + tid] = f2bf(accv);
    }
  }
}

// ---- GEMM stage wrappers ----

// G1: pu partials = uk @ W_in^T, split-K x4 (512 blocks, T=4)
__global__ __launch_bounds__(256, 4)
void g1_kernel(P p)
{
  __shared__ ushort_t sA[2][4608]; __shared__ ushort_t sB[2][4608];
  int bid = blockIdx.x, z = bid >> 7, rem = bid & 127;
  int my = rem >> 4, nx = rem & 15;
  gemm_tile<EPI_PART>(p.ukb, p.Winb, DM, z*256, 4, DM, my*64, nx*64,
                      p.PartA + (size_t)z*B_*DM, sA, sB, p, threadIdx.x);
}

// R1: Pu = bf16(sum4 partials + b_in)  (512 blocks x 256, 1 float4/thread)
__global__ __launch_bounds__(256)
void r1_kernel(P p)
{
  int i = (blockIdx.x*256 + threadIdx.x)*4;
  float4 s = *reinterpret_cast<const float4*>(p.PartA + i);
  #pragma unroll
  for (int z=1; z<4; ++z) {
    float4 t = *reinterpret_cast<const float4*>(p.PartA + (size_t)z*B_*DM + i);
    s.x+=t.x; s.y+=t.y; s.z+=t.z; s.w+=t.w;
  }
  float4 bv = *reinterpret_cast<const float4*>(p.b_in + (i & (DM-1)));
  s.x+=bv.x; s.y+=bv.y; s.z+=bv.z; s.w+=bv.w;
  *reinterpret_cast<uint2*>(p.Pu + i) = pack4(s);
}

// G2: xz = pu @ W_inproj^T (512 blocks, T=16), fused conv+silu / silu(z)
__global__ __launch_bounds__(256, 4)
void g2_kernel(P p)
{
  __shared__ ushort_t sA[2][4608]; __shared__ ushort_t sB[2][4608];
  int bid = blockIdx.x, my = bid >> 6, nx = bid & 63;
  gemm_tile<EPI_G2>(p.Pu, p.Wipb, DM, 0, 16, 2*DI, my*64, nx*64,
                    nullptr, sA, sB, p, threadIdx.x);
}

// G3: x_dbl partials = xs @ W_x^T, split-K x8 (192 blocks, T=4)
__global__ __launch_bounds__(256, 4)
void g3_kernel(P p)
{
  __shared__ ushort_t sA[2][4608]; __shared__ ushort_t sB[2][4608];
  int bid = blockIdx.x, z = bid / 24, rem = bid % 24;
  int my = rem / 3, nx = rem % 3;
  gemm_tile<EPI_PART>(p.Xs, p.Wxb, DI, z*256, 4, 192, my*64, nx*64,
                      p.PartC + (size_t)z*B_*192, sA, sB, p, threadIdx.x);
}

// R3: reduce 8 slices -> Acat[:,0:64] (dt_r) + bc[row] = dot(B_row, C_row)
__global__ __launch_bounds__(256)
void r3_kernel(P p)
{
  __shared__ float sBC[128];
  const int row = blockIdx.x, tid = threadIdx.x;
  if (tid < 192) {
    float s = 0.f;
    #pragma unroll
    for (int z=0; z<8; ++z) s += p.PartC[(size_t)z*B_*192 + (size_t)row*192 + tid];
    if (tid < 64) p.Acat[row*128 + tid] = f2bf(s);
    else          sBC[tid - 64] = s;
  }
  __syncthreads();
  if (tid < 64) {
    float pv = sBC[tid] * sBC[tid + 64];
    #pragma unroll
    for (int off=32; off; off>>=1) pv += __shfl_down(pv, off);
    if (tid == 0) p.bc[row] = pv;
  }
}

// G4: dt GEMM (K=128, B=Wcat) + softplus + y-fusion (256 blocks, T=2)
__global__ __launch_bounds__(256, 4)
void g4_kernel(P p)
{
  __shared__ ushort_t sA[2][4608]; __shared__ ushort_t sB[2][4608];
  int bid = blockIdx.x, my = bid >> 5, nx = bid & 31;
  gemm_tile<EPI_G4>(p.Acat, p.Wcat, 128, 0, 2, DI, my*64, nx*64,
                    nullptr, sA, sB, p, threadIdx.x);
}

// G5: hk partials = y @ W_out^T, split-K x4 (512 blocks, T=8)
__global__ __launch_bounds__(256, 4)
void g5_kernel(P p)
{
  __shared__ ushort_t sA[2][4608]; __shared__ ushort_t sB[2][4608];
  int bid = blockIdx.x, z = bid >> 7, rem = bid & 127;
  int my = rem >> 4, nx = rem & 15;
  gemm_tile<EPI_PART>(p.Yb, p.Woutb, DI, z*512, 8, DM, my*64, nx*64,
                      p.PartA + (size_t)z*B_*DM, sA, sB, p, threadIdx.x);
}

// R5: hk = sum4 partials (f32 out)
__global__ __launch_bounds__(256)
void r5_kernel(P p)
{
  int i = (blockIdx.x*256 + threadIdx.x)*4;
  float4 s = *reinterpret_cast<const float4*>(p.PartA + i);
  #pragma unroll
  for (int z=1; z<4; ++z) {
    float4 t = *reinterpret_cast<const float4*>(p.PartA + (size_t)z*B_*DM + i);
    s.x+=t.x; s.y+=t.y; s.z+=t.z; s.w+=t.w;
  }
  *reinterpret_cast<float4*>(p.out_hk + i) = s;
}

extern "C" void kernel_launch(void* const* d_in, const int* in_sizes, int n_in,
                              void* d_out, int out_size, void* d_ws, size_t ws_size,
                              hipStream_t stream)
{
  char* ws = (char*)d_ws;
  P p;
  p.uk      = (const float*)d_in[0];
  p.tk_c    = (const float*)d_in[1];
  p.tk_p    = (const float*)d_in[2];
  p.W_in    = (const float*)d_in[3];
  p.b_in    = (const float*)d_in[4];
  p.rW      = (const float*)d_in[5];
  p.rb      = (const float*)d_in[6];
  p.freq    = (const float*)d_in[7];
  p.phase   = (const float*)d_in[8];
  p.kanW    = (const float*)d_in[9];
  p.W_inproj= (const float*)d_in[10];
  p.conv_w  = (const float*)d_in[11];
  p.conv_b  = (const float*)d_in[12];
  p.W_x     = (const float*)d_in[13];
  p.W_dt    = (const float*)d_in[14];
  p.dt_bias = (const float*)d_in[15];
  p.W_delta = (const float*)d_in[16];
  /* d_in[17] = A_log — dead in the reference math */
  p.D_skip  = (const float*)d_in[18];
  p.W_out   = (const float*)d_in[19];

  const size_t MB = 1 << 20;
  p.ukb   = (__hip_bfloat16*)(ws + 0*MB);            // 1 MB
  p.Pu    = (__hip_bfloat16*)(ws + 1*MB);            // 1 MB
  p.Xs    = (__hip_bfloat16*)(ws + 2*MB);            // 2 MB
  p.Sz    = (__hip_bfloat16*)(ws + 4*MB);            // 2 MB
  p.Yb    = (__hip_bfloat16*)(ws + 6*MB);            // 2 MB
  p.Acat  = (__hip_bfloat16*)(ws + 8*MB);            // 128 KB
  p.bc    = (float*)         (ws + 8*MB + (256<<10));// 2 KB
  p.Winb  = (__hip_bfloat16*)(ws + 9*MB);            // 2 MB
  p.Wipb  = (__hip_bfloat16*)(ws + 11*MB);           // 8 MB
  p.Wxb   = (__hip_bfloat16*)(ws + 19*MB);           // 0.75 MB
  p.Woutb = (__hip_bfloat16*)(ws + 20*MB);           // 4 MB
  p.Wcat  = (__hip_bfloat16*)(ws + 24*MB);           // 0.5 MB
  p.PartA = (float*)         (ws + 25*MB);           // 8 MB (G1, then G5)
  p.PartC = (float*)         (ws + 33*MB);           // 3 MB (G3)

  p.out_hk   = (float*)d_out;
  p.out_w    = p.out_hk + (size_t)B_*DM;
  p.out_mask = p.out_w  + (size_t)B_*E_;

  prep_kernel<<<dim3(1024), dim3(256), 0, stream>>>(p);
  g1_kernel  <<<dim3(512),  dim3(256), 0, stream>>>(p);
  r1_kernel  <<<dim3(512),  dim3(256), 0, stream>>>(p);
  g2_kernel  <<<dim3(512),  dim3(256), 0, stream>>>(p);
  g3_kernel  <<<dim3(192),  dim3(256), 0, stream>>>(p);
  r3_kernel  <<<dim3(512),  dim3(256), 0, stream>>>(p);
  g4_kernel  <<<dim3(256),  dim3(256), 0, stream>>>(p);
  g5_kernel  <<<dim3(512),  dim3(256), 0, stream>>>(p);
  r5_kernel  <<<dim3(512),  dim3(256), 0, stream>>>(p);
}